// Round 2
// baseline (755.953 us; speedup 1.0000x reference)
//
#include <hip/hip_runtime.h>

typedef _Float16 f16;
typedef f16  f16x8 __attribute__((ext_vector_type(8)));
typedef f16  f16x4 __attribute__((ext_vector_type(4)));
typedef float f32x4 __attribute__((ext_vector_type(4)));

// ---- d_ws layout (f16 elems): hi/lo split weight arrays, 352,256 B total ----
#define W1T_HI 0        // [4][128][32]  W1T[e][u][f]
#define W1T_LO 16384
#define V1T_HI 32768    // [128][32]
#define V1T_LO 36864
#define W2T_HI 40960    // [4][64][160]  W2T[e][u][k], k = [h1(128), node(32)]
#define W2T_LO 81920
#define V2T_HI 122880   // [64][32]
#define V2T_LO 124928
#define WIT_HI 126976   // [128][96]     WiT[ua][k], k = [h2(64), node(32)]
#define WIT_LO 139264
#define WJT_HI 151552
#define WJT_LO 163840
#define WS_SRC 88064    // source f32 element count

// ---- dynamic LDS layout (f16 elems): 126,976 B = 124 KB -> 1 block/CU ----
#define ADJ_HI 0        // [4][64][64] XOR-swizzled (unit8 ^ (m&7))
#define ADJ_LO 16384
#define ANN_HI 32768    // [64][168]: cols 0..127 h1 (then 64..127 h2), 128..159 node
#define ANN_LO 43520
#define PT_HI  54272    // [64][72]: per-wave 16-row transposed P/Q slice
#define PT_LO  58880
#define LDS_BYTES 126976
#define ANN_S 168

__device__ __forceinline__ f32x4 mfma16(f16x8 a, f16x8 b, f32x4 c){
  return __builtin_amdgcn_mfma_f32_16x16x32_f16(a, b, c, 0, 0, 0);
}
__device__ __forceinline__ float fast_tanh(float x){
  x = fminf(15.f, fmaxf(-15.f, x));
  float e = __expf(2.f * x);
  return (e - 1.f) / (e + 1.f);
}
__device__ __forceinline__ float fast_sigmoid(float x){
  return 1.f / (1.f + __expf(-x));
}

__global__ void prep_weights(const float* __restrict__ W1, const float* __restrict__ V1,
                             const float* __restrict__ W2, const float* __restrict__ V2,
                             const float* __restrict__ Wi, const float* __restrict__ Wj,
                             f16* __restrict__ ws){
  int i = blockIdx.x * 256 + threadIdx.x;
  if (i >= WS_SRC) return;
  float v; int hi_off, idx;
  int j = i;
  if (j < 16384){ int e = j >> 12, u = (j >> 5) & 127, f = j & 31;
    v = W1[(e*32 + f)*128 + u]; hi_off = W1T_HI; idx = j; }
  else if ((j -= 16384) < 4096){ int u = j >> 5, f = j & 31;
    v = V1[f*128 + u]; hi_off = V1T_HI; idx = j; }
  else if ((j -= 4096) < 40960){ int e = j / 10240, r = j % 10240, u = r / 160, k = r % 160;
    v = W2[e*10240 + k*64 + u]; hi_off = W2T_HI; idx = j; }
  else if ((j -= 40960) < 2048){ int u = j >> 5, f = j & 31;
    v = V2[f*64 + u]; hi_off = V2T_HI; idx = j; }
  else if ((j -= 2048) < 12288){ int ua = j / 96, k = j % 96;
    v = Wi[k*128 + ua]; hi_off = WIT_HI; idx = j; }
  else { j -= 12288; int ua = j / 96, k = j % 96;
    v = Wj[k*128 + ua]; hi_off = WJT_HI; idx = j; }
  f16 h = (f16)v;
  ws[hi_off + idx] = h;
  ws[hi_off + (WIT_LO - WIT_HI) + idx] = (f16)(v - (float)h);  // lo array is +12288.. no:
}

// NOTE: lo offsets differ per array; fix with explicit lo_off instead (see below).
// (The kernel above is replaced by the correct version:)
__global__ void prep_weights2(const float* __restrict__ W1, const float* __restrict__ V1,
                              const float* __restrict__ W2, const float* __restrict__ V2,
                              const float* __restrict__ Wi, const float* __restrict__ Wj,
                              f16* __restrict__ ws){
  int i = blockIdx.x * 256 + threadIdx.x;
  if (i >= WS_SRC) return;
  float v; int hi_off, lo_off, idx;
  int j = i;
  if (j < 16384){ int e = j >> 12, u = (j >> 5) & 127, f = j & 31;
    v = W1[(e*32 + f)*128 + u]; hi_off = W1T_HI; lo_off = W1T_LO; idx = j; }
  else if ((j -= 16384) < 4096){ int u = j >> 5, f = j & 31;
    v = V1[f*128 + u]; hi_off = V1T_HI; lo_off = V1T_LO; idx = j; }
  else if ((j -= 4096) < 40960){ int e = j / 10240, r = j % 10240, u = r / 160, k = r % 160;
    v = W2[e*10240 + k*64 + u]; hi_off = W2T_HI; lo_off = W2T_LO; idx = j; }
  else if ((j -= 40960) < 2048){ int u = j >> 5, f = j & 31;
    v = V2[f*64 + u]; hi_off = V2T_HI; lo_off = V2T_LO; idx = j; }
  else if ((j -= 2048) < 12288){ int ua = j / 96, k = j % 96;
    v = Wi[k*128 + ua]; hi_off = WIT_HI; lo_off = WIT_LO; idx = j; }
  else { j -= 12288; int ua = j / 96, k = j % 96;
    v = Wj[k*128 + ua]; hi_off = WJT_HI; lo_off = WJT_LO; idx = j; }
  f16 h = (f16)v;
  ws[hi_off + idx] = h;
  ws[lo_off + idx] = (f16)(v - (float)h);
}

// Persistent: grid 256, 1 block/CU (124 KB LDS), 8 batches per block.
// fp32-quality GEMMs via 2-term fp16 splits, 3 MFMAs per product (drop lo*lo).
__global__ __launch_bounds__(256, 1) void encoder_main(
    const float* __restrict__ adj, const float* __restrict__ node,
    const float* __restrict__ b1, const float* __restrict__ c1,
    const float* __restrict__ b2, const float* __restrict__ c2,
    const float* __restrict__ bi, const float* __restrict__ bj,
    const f16* __restrict__ wb, float* __restrict__ out)
{
  extern __shared__ f16 lds[];
  const int tid  = threadIdx.x;
  const int w    = tid >> 6;
  const int lane = tid & 63;
  const int q    = lane >> 4;
  const int l15  = lane & 15;
  const f32x4 z4 = {0.f, 0.f, 0.f, 0.f};

  float  apf[8][8];       // adjacency prefetch: lane owns 8 n-units of 8 elems
  float4 npfa, npfb;      // node prefetch: lane owns 8 consecutive f of one row

  auto prefetch = [&](int BB){
    const float* ap = adj + (size_t)BB * 20480;
    #pragma unroll
    for (int uu = 0; uu < 8; ++uu){
      int fu = tid + 256*uu;                 // fu = (e*64 + m)*8 + uc
      int e = fu >> 9, m = (fu >> 3) & 63, uc = fu & 7;
      const float* p = ap + (m*64 + uc*8)*5 + e + 1;   // skip edge type 0
      #pragma unroll
      for (int jj = 0; jj < 8; ++jj) apf[uu][jj] = p[jj*5];
    }
    const float* np = node + (size_t)BB * 2048 + (tid & 63)*32 + (tid >> 6)*8;
    npfa = *(const float4*)np;
    npfb = *(const float4*)(np + 4);
  };

  prefetch(blockIdx.x);

  for (int it = 0; it < 8; ++it){
    const int bb = blockIdx.x + 256*it;
    __syncthreads();                         // prior batch done reading LDS
    // ---- convert prefetched fp32 -> split f16 LDS ----
    #pragma unroll
    for (int uu = 0; uu < 8; ++uu){
      int fu = tid + 256*uu;
      int e = fu >> 9, m = (fu >> 3) & 63, uc = fu & 7;
      f16x8 hi, lo;
      #pragma unroll
      for (int jj = 0; jj < 8; ++jj){
        float v = apf[uu][jj];
        f16 h = (f16)v; hi[jj] = h; lo[jj] = (f16)(v - (float)h);
      }
      int off = e*4096 + m*64 + ((uc ^ (m & 7))*8);    // XOR swizzle, 16B units
      *(f16x8*)&lds[ADJ_HI + off] = hi;
      *(f16x8*)&lds[ADJ_LO + off] = lo;
    }
    {
      int n = tid & 63, f0 = (tid >> 6)*8;
      float vv[8] = {npfa.x, npfa.y, npfa.z, npfa.w, npfb.x, npfb.y, npfb.z, npfb.w};
      f16x8 hi, lo;
      #pragma unroll
      for (int jj = 0; jj < 8; ++jj){
        f16 h = (f16)vv[jj]; hi[jj] = h; lo[jj] = (f16)(vv[jj] - (float)h);
      }
      *(f16x8*)&lds[ANN_HI + n*ANN_S + 128 + f0] = hi;
      *(f16x8*)&lds[ANN_LO + n*ANN_S + 128 + f0] = lo;
    }
    __syncthreads();
    if (it < 7) prefetch(blockIdx.x + 256*(it + 1));   // in flight during compute

    // ---- node A-fragments (hi/lo), reused everywhere ----
    f16x8 anh[4], anl[4];
    #pragma unroll
    for (int mt = 0; mt < 4; ++mt){
      anh[mt] = *(const f16x8*)&lds[ANN_HI + (mt*16 + l15)*ANN_S + 128 + q*8];
      anl[mt] = *(const f16x8*)&lds[ANN_LO + (mt*16 + l15)*ANN_S + 128 + q*8];
    }
    const int ptrow = (w*16 + l15)*72;

    // ================ layer 1 ================
    f32x4 acc1[4][2];
    #pragma unroll
    for (int mt = 0; mt < 4; ++mt){ acc1[mt][0] = z4; acc1[mt][1] = z4; }

    #pragma unroll
    for (int e = 0; e < 4; ++e){
      f16x8 ah[2][4], al[2][4];
      #pragma unroll
      for (int ks = 0; ks < 2; ++ks)
        #pragma unroll
        for (int mt = 0; mt < 4; ++mt){
          int off = e*4096 + (mt*16 + l15)*64 + (((ks*4 + q) ^ (l15 & 7))*8);
          ah[ks][mt] = *(const f16x8*)&lds[ADJ_HI + off];
          al[ks][mt] = *(const f16x8*)&lds[ADJ_LO + off];
        }
      #pragma unroll
      for (int ut = 0; ut < 2; ++ut){
        const int u = w*32 + ut*16 + l15;
        f16x8 wh = *(const f16x8*)&wb[W1T_HI + (e*128 + u)*32 + q*8];
        f16x8 wl = *(const f16x8*)&wb[W1T_LO + (e*128 + u)*32 + q*8];
        float bias = b1[e*128 + u];
        #pragma unroll
        for (int mt = 0; mt < 4; ++mt){
          f32x4 pf = mfma16(anh[mt], wh, z4);
          pf = mfma16(anl[mt], wh, pf);
          pf = mfma16(anh[mt], wl, pf);
          f16x4 ph, pl;
          #pragma unroll
          for (int r = 0; r < 4; ++r){
            float v = pf[r] + bias;
            f16 h = (f16)v; ph[r] = h; pl[r] = (f16)(v - (float)h);
          }
          *(f16x4*)&lds[PT_HI + ptrow + mt*16 + q*4] = ph;   // PT[u_loc][n]
          *(f16x4*)&lds[PT_LO + ptrow + mt*16 + q*4] = pl;
        }
        #pragma unroll
        for (int ks = 0; ks < 2; ++ks){
          f16x8 bph = *(const f16x8*)&lds[PT_HI + ptrow + ks*32 + q*8];
          f16x8 bpl = *(const f16x8*)&lds[PT_LO + ptrow + ks*32 + q*8];
          #pragma unroll
          for (int mt = 0; mt < 4; ++mt){
            acc1[mt][ut] = mfma16(ah[ks][mt], bph, acc1[mt][ut]);
            acc1[mt][ut] = mfma16(al[ks][mt], bph, acc1[mt][ut]);
            acc1[mt][ut] = mfma16(ah[ks][mt], bpl, acc1[mt][ut]);
          }
        }
      }
    }
    #pragma unroll
    for (int ut = 0; ut < 2; ++ut){
      const int u = w*32 + ut*16 + l15;
      f16x8 wh = *(const f16x8*)&wb[V1T_HI + u*32 + q*8];
      f16x8 wl = *(const f16x8*)&wb[V1T_LO + u*32 + q*8];
      float cv = c1[u];
      #pragma unroll
      for (int mt = 0; mt < 4; ++mt){
        f32x4 a = acc1[mt][ut];
        a = mfma16(anh[mt], wh, a);
        a = mfma16(anl[mt], wh, a);
        a = mfma16(anh[mt], wl, a);
        #pragma unroll
        for (int r = 0; r < 4; ++r){
          float h = fast_tanh(a[r] + cv);
          f16 hh = (f16)h;
          lds[ANN_HI + (mt*16 + q*4 + r)*ANN_S + u] = hh;          // h1 cols 0..127
          lds[ANN_LO + (mt*16 + q*4 + r)*ANN_S + u] = (f16)(h - (float)hh);
        }
      }
    }
    __syncthreads();

    // ================ layer 2 ================
    const int u2 = w*16 + l15;
    f16x8 w2h[4][5], w2l[4][5];
    #pragma unroll
    for (int e = 0; e < 4; ++e)
      #pragma unroll
      for (int ks = 0; ks < 5; ++ks){
        w2h[e][ks] = *(const f16x8*)&wb[W2T_HI + (e*64 + u2)*160 + ks*32 + q*8];
        w2l[e][ks] = *(const f16x8*)&wb[W2T_LO + (e*64 + u2)*160 + ks*32 + q*8];
      }
    f32x4 qf[4][4];                          // [e][mt], dense phase mt-outer
    #pragma unroll
    for (int mt = 0; mt < 4; ++mt){
      f16x8 axh[4], axl[4];
      #pragma unroll
      for (int ks = 0; ks < 4; ++ks){
        axh[ks] = *(const f16x8*)&lds[ANN_HI + (mt*16 + l15)*ANN_S + ks*32 + q*8];
        axl[ks] = *(const f16x8*)&lds[ANN_LO + (mt*16 + l15)*ANN_S + ks*32 + q*8];
      }
      #pragma unroll
      for (int e = 0; e < 4; ++e){
        f32x4 t = mfma16(anh[mt], w2h[e][4], z4);   // node part k=128..159
        t = mfma16(anl[mt], w2h[e][4], t);
        t = mfma16(anh[mt], w2l[e][4], t);
        #pragma unroll
        for (int ks = 0; ks < 4; ++ks){
          t = mfma16(axh[ks], w2h[e][ks], t);
          t = mfma16(axl[ks], w2h[e][ks], t);
          t = mfma16(axh[ks], w2l[e][ks], t);
        }
        qf[e][mt] = t;
      }
    }
    f32x4 acc2[4];
    #pragma unroll
    for (int mt = 0; mt < 4; ++mt) acc2[mt] = z4;
    #pragma unroll
    for (int e = 0; e < 4; ++e){
      f16x8 ah[2][4], al[2][4];
      #pragma unroll
      for (int ks = 0; ks < 2; ++ks)
        #pragma unroll
        for (int mt = 0; mt < 4; ++mt){
          int off = e*4096 + (mt*16 + l15)*64 + (((ks*4 + q) ^ (l15 & 7))*8);
          ah[ks][mt] = *(const f16x8*)&lds[ADJ_HI + off];
          al[ks][mt] = *(const f16x8*)&lds[ADJ_LO + off];
        }
      float bias = b2[e*64 + u2];
      #pragma unroll
      for (int mt = 0; mt < 4; ++mt){
        f16x4 ph, pl;
        #pragma unroll
        for (int r = 0; r < 4; ++r){
          float v = qf[e][mt][r] + bias;
          f16 h = (f16)v; ph[r] = h; pl[r] = (f16)(v - (float)h);
        }
        *(f16x4*)&lds[PT_HI + ptrow + mt*16 + q*4] = ph;   // QT[u_loc][n]
        *(f16x4*)&lds[PT_LO + ptrow + mt*16 + q*4] = pl;
      }
      #pragma unroll
      for (int ks = 0; ks < 2; ++ks){
        f16x8 bph = *(const f16x8*)&lds[PT_HI + ptrow + ks*32 + q*8];
        f16x8 bpl = *(const f16x8*)&lds[PT_LO + ptrow + ks*32 + q*8];
        #pragma unroll
        for (int mt = 0; mt < 4; ++mt){
          acc2[mt] = mfma16(ah[ks][mt], bph, acc2[mt]);
          acc2[mt] = mfma16(al[ks][mt], bph, acc2[mt]);
          acc2[mt] = mfma16(ah[ks][mt], bpl, acc2[mt]);
        }
      }
    }
    {
      f16x8 wh = *(const f16x8*)&wb[V2T_HI + u2*32 + q*8];
      f16x8 wl = *(const f16x8*)&wb[V2T_LO + u2*32 + q*8];
      #pragma unroll
      for (int mt = 0; mt < 4; ++mt){
        acc2[mt] = mfma16(anh[mt], wh, acc2[mt]);
        acc2[mt] = mfma16(anl[mt], wh, acc2[mt]);
        acc2[mt] = mfma16(anh[mt], wl, acc2[mt]);
      }
    }
    __syncthreads();                          // all waves done reading h1
    {
      float cv = c2[u2];
      #pragma unroll
      for (int mt = 0; mt < 4; ++mt)
        #pragma unroll
        for (int r = 0; r < 4; ++r){
          float h = fast_tanh(acc2[mt][r] + cv);
          f16 hh = (f16)h;
          lds[ANN_HI + (mt*16 + q*4 + r)*ANN_S + 64 + u2] = hh;    // h2 cols 64..127
          lds[ANN_LO + (mt*16 + q*4 + r)*ANN_S + 64 + u2] = (f16)(h - (float)hh);
        }
    }
    __syncthreads();

    // ================ aggregation ================
    f16x8 wih[2][3], wil[2][3], wjh[2][3], wjl[2][3];
    float bib[2], bjb[2];
    #pragma unroll
    for (int ut = 0; ut < 2; ++ut){
      const int ua = w*32 + ut*16 + l15;
      #pragma unroll
      for (int ks = 0; ks < 3; ++ks){
        wih[ut][ks] = *(const f16x8*)&wb[WIT_HI + ua*96 + ks*32 + q*8];
        wil[ut][ks] = *(const f16x8*)&wb[WIT_LO + ua*96 + ks*32 + q*8];
        wjh[ut][ks] = *(const f16x8*)&wb[WJT_HI + ua*96 + ks*32 + q*8];
        wjl[ut][ks] = *(const f16x8*)&wb[WJT_LO + ua*96 + ks*32 + q*8];
      }
      bib[ut] = bi[ua]; bjb[ut] = bj[ua];
    }
    float s[2] = {0.f, 0.f};
    #pragma unroll
    for (int mt = 0; mt < 4; ++mt){
      f16x8 gh[2], gl[2];
      #pragma unroll
      for (int ks = 0; ks < 2; ++ks){
        gh[ks] = *(const f16x8*)&lds[ANN_HI + (mt*16 + l15)*ANN_S + 64 + ks*32 + q*8];
        gl[ks] = *(const f16x8*)&lds[ANN_LO + (mt*16 + l15)*ANN_S + 64 + ks*32 + q*8];
      }
      #pragma unroll
      for (int ut = 0; ut < 2; ++ut){
        f32x4 ia = mfma16(anh[mt], wih[ut][2], z4);
        ia = mfma16(anl[mt], wih[ut][2], ia);
        ia = mfma16(anh[mt], wil[ut][2], ia);
        f32x4 ja = mfma16(anh[mt], wjh[ut][2], z4);
        ja = mfma16(anl[mt], wjh[ut][2], ja);
        ja = mfma16(anh[mt], wjl[ut][2], ja);
        #pragma unroll
        for (int ks = 0; ks < 2; ++ks){
          ia = mfma16(gh[ks], wih[ut][ks], ia);
          ia = mfma16(gl[ks], wih[ut][ks], ia);
          ia = mfma16(gh[ks], wil[ut][ks], ia);
          ja = mfma16(gh[ks], wjh[ut][ks], ja);
          ja = mfma16(gl[ks], wjh[ut][ks], ja);
          ja = mfma16(gh[ks], wjl[ut][ks], ja);
        }
        #pragma unroll
        for (int r = 0; r < 4; ++r)
          s[ut] += fast_sigmoid(ia[r] + bib[ut]) * fast_tanh(ja[r] + bjb[ut]);
      }
    }
    #pragma unroll
    for (int ut = 0; ut < 2; ++ut){
      float t = s[ut];
      t += __shfl_xor(t, 16);
      t += __shfl_xor(t, 32);
      if (q == 0) out[(size_t)bb*128 + (w*32 + ut*16 + l15)] = fast_tanh(t);
    }
  }
}

extern "C" void kernel_launch(void* const* d_in, const int* in_sizes, int n_in,
                              void* d_out, int out_size, void* d_ws, size_t ws_size,
                              hipStream_t stream) {
  (void)in_sizes; (void)n_in; (void)out_size; (void)ws_size;
  const float* adj  = (const float*)d_in[0];
  // d_in[1] = hidden (zeros, rank-2): unused by the reference path
  const float* node = (const float*)d_in[2];
  const float* W1   = (const float*)d_in[3];
  const float* b1   = (const float*)d_in[4];
  const float* V1   = (const float*)d_in[5];
  const float* c1   = (const float*)d_in[6];
  const float* W2   = (const float*)d_in[7];
  const float* b2   = (const float*)d_in[8];
  const float* V2   = (const float*)d_in[9];
  const float* c2   = (const float*)d_in[10];
  const float* Wi   = (const float*)d_in[11];
  const float* bi   = (const float*)d_in[12];
  const float* Wj   = (const float*)d_in[13];
  const float* bj   = (const float*)d_in[14];
  f16* wb    = (f16*)d_ws;
  float* out = (float*)d_out;

  static_assert(LDS_BYTES <= 131072, "LDS budget");
  hipFuncSetAttribute((const void*)encoder_main,
                      hipFuncAttributeMaxDynamicSharedMemorySize, LDS_BYTES);

  prep_weights2<<<(WS_SRC + 255) / 256, 256, 0, stream>>>(W1, V1, W2, V2, Wi, Wj, wb);
  encoder_main<<<256, 256, LDS_BYTES, stream>>>(adj, node, b1, c1, b2, c2, bi, bj, wb, out);
}

// Round 5
// 407.563 us; speedup vs baseline: 1.8548x; 1.8548x over previous
//
#include <hip/hip_runtime.h>

typedef _Float16 f16;
typedef f16  f16x8 __attribute__((ext_vector_type(8)));
typedef f16  f16x4 __attribute__((ext_vector_type(4)));
typedef float f32x4 __attribute__((ext_vector_type(4)));
typedef unsigned int u32;

// ---- d_ws layout (f16 elems): hi/lo split weights, 352,256 B ----
#define W1T_HI 0        // [4][128][32]  W1T[e][u][f]
#define W1T_LO 16384
#define V1T_HI 32768    // [128][32]
#define V1T_LO 36864
#define W2T_HI 40960    // [4][64][160]  W2T[e][u][k], k = [h1(128), node(32)]
#define W2T_LO 81920
#define V2T_HI 122880   // [64][32]
#define V2T_LO 124928
#define WIT_HI 126976   // [128][96]     WiT[ua][k], k = [h2(64), node(32)]
#define WIT_LO 139264
#define WJT_HI 151552
#define WJT_LO 163840
#define WS_SRC 88064

// ---- dynamic LDS (bytes): 81,920 B = 80 KB -> 2 blocks/CU ----
// ANNB_LO cols 0..63 (bytes row*128+0..63) are liveness-overlaid as the
// 8-bit PT_LO plane (dead whenever the other is alive; barriers fence it).
// PTB region doubles as node staging: hi [64][32] f16 + lo [64][32] f16.
#define ADJB_HI 0        // f16 [4][64][64], XOR swizzle (unit8 ^ (m&7))      32768 B
#define ADJB_LO 32768    // u8  [4][64][64], same swizzle, byte-interleaved   16384 B
#define ANNB_HI 49152    // f16 [64][128]: h1 (h2 overlays cols 64..127)      16384 B
#define ANNB_LO 65536    // u8  [64][128]; cols 0..63 overlay = PT_LO          8192 B
#define PTB     73728    // f16 [64][64] per-wave transposed P/Q; node overlay 8192 B
#define LDS_BYTES 81920

__device__ __forceinline__ f32x4 mfma16(f16x8 a, f16x8 b, f32x4 c){
  return __builtin_amdgcn_mfma_f32_16x16x32_f16(a, b, c, 0, 0, 0);
}
__device__ __forceinline__ float fast_tanh(float x){
  x = fminf(15.f, fmaxf(-15.f, x));
  float e = __expf(2.f * x);
  return (e - 1.f) / (e + 1.f);
}
__device__ __forceinline__ float fast_sigmoid(float x){
  return 1.f / (1.f + __expf(-x));
}

// ---- 8-bit lo-plane codec: byte = sign + bits 13:7 of f16(lo) (4 exp + 3 man,
// round-to-nearest). Valid while |lo| < 2 (always: |lo| <= ulp/2 of an f16).
// decode: sign<<15 | (b&0x7f)<<7 == f16(lo) up to 3-bit mantissa truncation.
__device__ __forceinline__ unsigned char enc1(float lo){
  f16 h = (f16)lo;
  unsigned short u = __builtin_bit_cast(unsigned short, h);
  return (unsigned char)(((u >> 8) & 0x80u) | (((u & 0x7fffu) + 0x40u) >> 7));
}
__device__ __forceinline__ int bpos(int j){          // byte interleave 0,2,1,3|4,6,5,7
  return (j & 4) | ((j & 1) << 1) | ((j & 2) >> 1);
}
__device__ __forceinline__ void enc8(unsigned char* p, const float* lo){
  unsigned char t[8];
  #pragma unroll
  for (int j = 0; j < 8; ++j) t[bpos(j)] = enc1(lo[j]);
  uint2 v; __builtin_memcpy(&v, t, 8);
  *(uint2*)p = v;
}
// pack 4 logical bytes j0..j3 at phys (j0, j2, j1, j3) — dec8-compatible half-unit
__device__ __forceinline__ u32 enc4(const float* lo){
  u32 b0 = enc1(lo[0]), b1 = enc1(lo[1]), b2 = enc1(lo[2]), b3 = enc1(lo[3]);
  return b0 | (b2 << 8) | (b1 << 16) | (b3 << 24);
}
__device__ __forceinline__ f16x8 dec8(const unsigned char* p){
  uint2 d = *(const uint2*)p;
  u32 w[4];
  w[0] = ((d.x & 0x00800080u) << 8) | ((d.x & 0x007f007fu) << 7);
  u32 t0 = d.x >> 8;
  w[1] = ((t0 & 0x00800080u) << 8) | ((t0 & 0x007f007fu) << 7);
  w[2] = ((d.y & 0x00800080u) << 8) | ((d.y & 0x007f007fu) << 7);
  u32 t1 = d.y >> 8;
  w[3] = ((t1 & 0x00800080u) << 8) | ((t1 & 0x007f007fu) << 7);
  f16x8 r; __builtin_memcpy(&r, w, 16);
  return r;
}

__global__ void prep_weights(const float* __restrict__ W1, const float* __restrict__ V1,
                             const float* __restrict__ W2, const float* __restrict__ V2,
                             const float* __restrict__ Wi, const float* __restrict__ Wj,
                             f16* __restrict__ ws){
  int i = blockIdx.x * 256 + threadIdx.x;
  if (i >= WS_SRC) return;
  float v; int hi_off, lo_off, idx;
  int j = i;
  if (j < 16384){ int e = j >> 12, u = (j >> 5) & 127, f = j & 31;
    v = W1[(e*32 + f)*128 + u]; hi_off = W1T_HI; lo_off = W1T_LO; idx = j; }
  else if ((j -= 16384) < 4096){ int u = j >> 5, f = j & 31;
    v = V1[f*128 + u]; hi_off = V1T_HI; lo_off = V1T_LO; idx = j; }
  else if ((j -= 4096) < 40960){ int e = j / 10240, r = j % 10240, u = r / 160, k = r % 160;
    v = W2[e*10240 + k*64 + u]; hi_off = W2T_HI; lo_off = W2T_LO; idx = j; }
  else if ((j -= 40960) < 2048){ int u = j >> 5, f = j & 31;
    v = V2[f*64 + u]; hi_off = V2T_HI; lo_off = V2T_LO; idx = j; }
  else if ((j -= 2048) < 12288){ int ua = j / 96, k = j % 96;
    v = Wi[k*128 + ua]; hi_off = WIT_HI; lo_off = WIT_LO; idx = j; }
  else { j -= 12288; int ua = j / 96, k = j % 96;
    v = Wj[k*128 + ua]; hi_off = WJT_HI; lo_off = WJT_LO; idx = j; }
  f16 h = (f16)v;
  ws[hi_off + idx] = h;
  ws[lo_off + idx] = (f16)(v - (float)h);
}

// one block = one batch; 4 waves; 80 KB LDS -> 2 blocks/CU for phase overlap.
__global__ __launch_bounds__(256, 2) void encoder_main(
    const float* __restrict__ adj, const float* __restrict__ node,
    const float* __restrict__ b1, const float* __restrict__ c1,
    const float* __restrict__ b2, const float* __restrict__ c2,
    const float* __restrict__ bi, const float* __restrict__ bj,
    const f16* __restrict__ wb, float* __restrict__ out)
{
  extern __shared__ unsigned char ldsb[];
  f16* adjh            = (f16*)(ldsb + ADJB_HI);
  unsigned char* adjl  = ldsb + ADJB_LO;
  f16* annh            = (f16*)(ldsb + ANNB_HI);
  unsigned char* annl  = ldsb + ANNB_LO;   // cols 0..63 double as PT_LO
  unsigned char* ptb   = ldsb + PTB;       // f16 [64][64], byte-addressed
  f16* nodeH           = (f16*)(ldsb + PTB);          // staging overlay
  f16* nodeLo          = (f16*)(ldsb + PTB + 4096);   // staging overlay

  const int tid  = threadIdx.x;
  const int w    = tid >> 6;
  const int lane = tid & 63;
  const int q    = lane >> 4;
  const int l15  = lane & 15;
  const int b    = blockIdx.x;
  const f32x4 z4 = {0.f, 0.f, 0.f, 0.f};

  // ---------------- stage: adjacency + node -> split LDS ----------------
  {
    const float* ap = adj + (size_t)b * 20480;
    #pragma unroll
    for (int i = 0; i < 8; ++i){
      int fu = tid + 256*i;                       // fu = (e*64 + m)*8 + uc
      int e = fu >> 9, m = (fu >> 3) & 63, uc = fu & 7;
      const float* p = ap + (m*64 + uc*8)*5 + e + 1;    // skip edge type 0
      float v[8], lo[8]; f16x8 hi;
      #pragma unroll
      for (int jj = 0; jj < 8; ++jj) v[jj] = p[jj*5];
      #pragma unroll
      for (int jj = 0; jj < 8; ++jj){
        f16 h = (f16)v[jj]; hi[jj] = h; lo[jj] = v[jj] - (float)h;
      }
      int off = e*4096 + m*64 + ((uc ^ (m & 7)) * 8);
      *(f16x8*)&adjh[off] = hi;
      enc8(&adjl[off], lo);
    }
    const float* np = node + (size_t)b * 2048 + (tid & 63)*32 + (tid >> 6)*8;
    float4 a = *(const float4*)np, c = *(const float4*)(np + 4);
    float v[8] = {a.x, a.y, a.z, a.w, c.x, c.y, c.z, c.w};
    f16x8 hi, lo;
    #pragma unroll
    for (int jj = 0; jj < 8; ++jj){
      f16 h = (f16)v[jj]; hi[jj] = h; lo[jj] = (f16)(v[jj] - (float)h);
    }
    int n = tid & 63, un = tid >> 6;
    *(f16x8*)&nodeH [n*32 + ((un ^ (n & 3)) * 8)] = hi;
    *(f16x8*)&nodeLo[n*32 + ((un ^ (n & 3)) * 8)] = lo;
  }
  __syncthreads();

  // node A-frags hi+lo (registers; node LDS region dead after this + barrier)
  f16x8 anh[4], anl[4];
  #pragma unroll
  for (int mt = 0; mt < 4; ++mt){
    anh[mt] = *(const f16x8*)&nodeH [(mt*16 + l15)*32 + ((q ^ (l15 & 3)) * 8)];
    anl[mt] = *(const f16x8*)&nodeLo[(mt*16 + l15)*32 + ((q ^ (l15 & 3)) * 8)];
  }
  __syncthreads();                                // protect PT/node overlay

  const int ptrow  = (w*16 + l15) * 128;          // PT_HI row byte offset
  const int ptlrow = (w*16 + l15) * 128;          // PT_LO row byte offset (in annl)

  // ============ layer 1: h1 = tanh(sum_e A_e(node@W1+b1) + node@V1 + c1) ============
  f32x4 acc1[4][2];
  #pragma unroll
  for (int mt = 0; mt < 4; ++mt){ acc1[mt][0] = z4; acc1[mt][1] = z4; }

  #pragma unroll
  for (int e = 0; e < 4; ++e){
    f16x8 ah[2][4], al[2][4];
    #pragma unroll
    for (int ks = 0; ks < 2; ++ks)
      #pragma unroll
      for (int mt = 0; mt < 4; ++mt){
        int off = e*4096 + (mt*16 + l15)*64 + (((ks*4 + q) ^ (l15 & 7)) * 8);
        ah[ks][mt] = *(const f16x8*)&adjh[off];
        al[ks][mt] = dec8(&adjl[off]);
      }
    #pragma unroll
    for (int ut = 0; ut < 2; ++ut){
      const int u = w*32 + ut*16 + l15;
      f16x8 wh = *(const f16x8*)&wb[W1T_HI + (e*128 + u)*32 + q*8];
      f16x8 wl = *(const f16x8*)&wb[W1T_LO + (e*128 + u)*32 + q*8];
      float bias = b1[e*128 + u];
      #pragma unroll
      for (int mt = 0; mt < 4; ++mt){
        f32x4 pf = mfma16(anh[mt], wh, z4);
        pf = mfma16(anl[mt], wh, pf);
        pf = mfma16(anh[mt], wl, pf);
        f16x4 ph; float lo4[4];
        #pragma unroll
        for (int r = 0; r < 4; ++r){
          float v = pf[r] + bias;
          f16 h = (f16)v; ph[r] = h; lo4[r] = v - (float)h;
        }
        int unit = ((mt*2 + (q >> 1)) ^ (l15 & 7));      // n0 = mt*16+q*4
        *(f16x4*)(ptb + ptrow + unit*16 + (q & 1)*8) = ph;     // PT_HI[u_loc][n]
        *(u32*)(annl + ptlrow + unit*8 + (q & 1)*4) = enc4(lo4); // PT_LO overlay
      }
      #pragma unroll
      for (int ks = 0; ks < 2; ++ks){
        int pu = ((ks*4 + q) ^ (l15 & 7));
        f16x8 bph = *(const f16x8*)(ptb + ptrow + pu*16);
        f16x8 bpl = dec8(annl + ptlrow + pu*8);
        #pragma unroll
        for (int mt = 0; mt < 4; ++mt){
          acc1[mt][ut] = mfma16(ah[ks][mt], bph, acc1[mt][ut]);
          acc1[mt][ut] = mfma16(al[ks][mt], bph, acc1[mt][ut]);
          acc1[mt][ut] = mfma16(ah[ks][mt], bpl, acc1[mt][ut]);
        }
      }
    }
  }
  __syncthreads();      // PT_LO reads done before ANN_LO cols0..63 h1 writes

  #pragma unroll
  for (int ut = 0; ut < 2; ++ut){
    const int u = w*32 + ut*16 + l15;
    f16x8 wh = *(const f16x8*)&wb[V1T_HI + u*32 + q*8];
    f16x8 wl = *(const f16x8*)&wb[V1T_LO + u*32 + q*8];
    float cv = c1[u];
    #pragma unroll
    for (int mt = 0; mt < 4; ++mt){
      f32x4 a = acc1[mt][ut];
      a = mfma16(anh[mt], wh, a);
      a = mfma16(anl[mt], wh, a);
      a = mfma16(anh[mt], wl, a);
      #pragma unroll
      for (int r = 0; r < 4; ++r){
        float h = fast_tanh(a[r] + cv);
        f16 hh = (f16)h;
        int row = mt*16 + q*4 + r;
        int unit = ((u >> 3) ^ (row & 7));
        annh[row*128 + unit*8 + (u & 7)] = hh;                   // h1 cols 0..127
        annl[row*128 + unit*8 + bpos(u & 7)] = enc1(h - (float)hh);
      }
    }
  }
  __syncthreads();

  // ============ layer 2: h2 = tanh(sum_e A_e(ann@W2+b2) + node@V2 + c2) ============
  const int u2 = w*16 + l15;
  f32x4 qf[4][4];                                 // [e][mt]
  #pragma unroll
  for (int mt = 0; mt < 4; ++mt){
    f16x8 axh[4], axl[4];
    #pragma unroll
    for (int ks = 0; ks < 4; ++ks){
      int off = (mt*16 + l15)*128 + (((ks*4 + q) ^ (l15 & 7)) * 8);
      axh[ks] = *(const f16x8*)&annh[off];
      axl[ks] = dec8(&annl[off]);
    }
    #pragma unroll
    for (int e = 0; e < 4; ++e){
      const f16* w2h = &wb[W2T_HI + (e*64 + u2)*160];
      const f16* w2l = &wb[W2T_LO + (e*64 + u2)*160];
      f16x8 wnh = *(const f16x8*)&w2h[4*32 + q*8];
      f16x8 wnl = *(const f16x8*)&w2l[4*32 + q*8];
      f32x4 t = mfma16(anh[mt], wnh, z4);          // node part k=128..159
      t = mfma16(anl[mt], wnh, t);
      t = mfma16(anh[mt], wnl, t);
      #pragma unroll
      for (int ks = 0; ks < 4; ++ks){
        f16x8 wh = *(const f16x8*)&w2h[ks*32 + q*8];
        f16x8 wl = *(const f16x8*)&w2l[ks*32 + q*8];
        t = mfma16(axh[ks], wh, t);
        t = mfma16(axl[ks], wh, t);
        t = mfma16(axh[ks], wl, t);
      }
      qf[e][mt] = t;
    }
  }
  __syncthreads();      // ANN_LO cols0..63 reads done before QT_LO writes

  f32x4 acc2[4];
  #pragma unroll
  for (int mt = 0; mt < 4; ++mt) acc2[mt] = z4;
  #pragma unroll
  for (int e = 0; e < 4; ++e){
    float bias = b2[e*64 + u2];
    #pragma unroll
    for (int mt = 0; mt < 4; ++mt){
      f16x4 ph; float lo4[4];
      #pragma unroll
      for (int r = 0; r < 4; ++r){
        float v = qf[e][mt][r] + bias;
        f16 h = (f16)v; ph[r] = h; lo4[r] = v - (float)h;
      }
      int unit = ((mt*2 + (q >> 1)) ^ (l15 & 7));
      *(f16x4*)(ptb + ptrow + unit*16 + (q & 1)*8) = ph;       // QT_HI[u_loc][n]
      *(u32*)(annl + ptlrow + unit*8 + (q & 1)*4) = enc4(lo4); // QT_LO overlay
    }
    #pragma unroll
    for (int ks = 0; ks < 2; ++ks){
      int pu = ((ks*4 + q) ^ (l15 & 7));
      f16x8 bph = *(const f16x8*)(ptb + ptrow + pu*16);
      f16x8 bpl = dec8(annl + ptlrow + pu*8);
      #pragma unroll
      for (int mt = 0; mt < 4; ++mt){
        int off = e*4096 + (mt*16 + l15)*64 + (((ks*4 + q) ^ (l15 & 7)) * 8);
        f16x8 ah = *(const f16x8*)&adjh[off];
        f16x8 al = dec8(&adjl[off]);
        acc2[mt] = mfma16(ah, bph, acc2[mt]);
        acc2[mt] = mfma16(al, bph, acc2[mt]);
        acc2[mt] = mfma16(ah, bpl, acc2[mt]);
      }
    }
  }
  {
    f16x8 wh = *(const f16x8*)&wb[V2T_HI + u2*32 + q*8];
    f16x8 wl = *(const f16x8*)&wb[V2T_LO + u2*32 + q*8];
    #pragma unroll
    for (int mt = 0; mt < 4; ++mt){
      acc2[mt] = mfma16(anh[mt], wh, acc2[mt]);
      acc2[mt] = mfma16(anl[mt], wh, acc2[mt]);
      acc2[mt] = mfma16(anh[mt], wl, acc2[mt]);
    }
  }
  // h2 epilogue writes ANN cols 64..127 (units 8..15) — disjoint from QT_LO
  // (units 0..7) and from other waves' QT rows, so no barrier needed here.
  {
    float cv = c2[u2];
    const int uc = 64 + u2;
    #pragma unroll
    for (int mt = 0; mt < 4; ++mt)
      #pragma unroll
      for (int r = 0; r < 4; ++r){
        float h = fast_tanh(acc2[mt][r] + cv);
        f16 hh = (f16)h;
        int row = mt*16 + q*4 + r;
        int unit = ((uc >> 3) ^ (row & 7));
        annh[row*128 + unit*8 + (uc & 7)] = hh;                  // h2 cols 64..127
        annl[row*128 + unit*8 + bpos(uc & 7)] = enc1(h - (float)hh);
      }
  }
  __syncthreads();

  // ============ aggregation: out = tanh(sum_n sigmoid(.)·tanh(.)) ============
  f16x8 wih[2][3], wil[2][3], wjh[2][3], wjl[2][3];
  float bib[2], bjb[2];
  #pragma unroll
  for (int ut = 0; ut < 2; ++ut){
    const int ua = w*32 + ut*16 + l15;
    #pragma unroll
    for (int ks = 0; ks < 3; ++ks){
      wih[ut][ks] = *(const f16x8*)&wb[WIT_HI + ua*96 + ks*32 + q*8];
      wil[ut][ks] = *(const f16x8*)&wb[WIT_LO + ua*96 + ks*32 + q*8];
      wjh[ut][ks] = *(const f16x8*)&wb[WJT_HI + ua*96 + ks*32 + q*8];
      wjl[ut][ks] = *(const f16x8*)&wb[WJT_LO + ua*96 + ks*32 + q*8];
    }
    bib[ut] = bi[ua]; bjb[ut] = bj[ua];
  }
  float s[2] = {0.f, 0.f};
  #pragma unroll
  for (int mt = 0; mt < 4; ++mt){
    f16x8 gh[2], gl[2];
    #pragma unroll
    for (int ks = 0; ks < 2; ++ks){
      int off = (mt*16 + l15)*128 + (((8 + ks*4 + q) ^ (l15 & 7)) * 8);
      gh[ks] = *(const f16x8*)&annh[off];
      gl[ks] = dec8(&annl[off]);
    }
    #pragma unroll
    for (int ut = 0; ut < 2; ++ut){
      f32x4 ia = mfma16(anh[mt], wih[ut][2], z4);   // node part k=64..95
      ia = mfma16(anl[mt], wih[ut][2], ia);
      ia = mfma16(anh[mt], wil[ut][2], ia);
      f32x4 ja = mfma16(anh[mt], wjh[ut][2], z4);
      ja = mfma16(anl[mt], wjh[ut][2], ja);
      ja = mfma16(anh[mt], wjl[ut][2], ja);
      #pragma unroll
      for (int ks = 0; ks < 2; ++ks){
        ia = mfma16(gh[ks], wih[ut][ks], ia);
        ia = mfma16(gl[ks], wih[ut][ks], ia);
        ia = mfma16(gh[ks], wil[ut][ks], ia);
        ja = mfma16(gh[ks], wjh[ut][ks], ja);
        ja = mfma16(gl[ks], wjh[ut][ks], ja);
        ja = mfma16(gh[ks], wjl[ut][ks], ja);
      }
      #pragma unroll
      for (int r = 0; r < 4; ++r)
        s[ut] += fast_sigmoid(ia[r] + bib[ut]) * fast_tanh(ja[r] + bjb[ut]);
    }
  }
  #pragma unroll
  for (int ut = 0; ut < 2; ++ut){
    float t = s[ut];
    t += __shfl_xor(t, 16);
    t += __shfl_xor(t, 32);
    if (q == 0) out[(size_t)b*128 + (w*32 + ut*16 + l15)] = fast_tanh(t);
  }
}

extern "C" void kernel_launch(void* const* d_in, const int* in_sizes, int n_in,
                              void* d_out, int out_size, void* d_ws, size_t ws_size,
                              hipStream_t stream) {
  (void)in_sizes; (void)n_in; (void)out_size; (void)ws_size;
  const float* adj  = (const float*)d_in[0];
  // d_in[1] = hidden (zeros, rank-2): unused by the reference path
  const float* node = (const float*)d_in[2];
  const float* W1   = (const float*)d_in[3];
  const float* b1   = (const float*)d_in[4];
  const float* V1   = (const float*)d_in[5];
  const float* c1   = (const float*)d_in[6];
  const float* W2   = (const float*)d_in[7];
  const float* b2   = (const float*)d_in[8];
  const float* V2   = (const float*)d_in[9];
  const float* c2   = (const float*)d_in[10];
  const float* Wi   = (const float*)d_in[11];
  const float* bi   = (const float*)d_in[12];
  const float* Wj   = (const float*)d_in[13];
  const float* bj   = (const float*)d_in[14];
  f16* wb    = (f16*)d_ws;
  float* out = (float*)d_out;

  hipFuncSetAttribute((const void*)encoder_main,
                      hipFuncAttributeMaxDynamicSharedMemorySize, LDS_BYTES);

  prep_weights<<<(WS_SRC + 255) / 256, 256, 0, stream>>>(W1, V1, W2, V2, Wi, Wj, wb);
  encoder_main<<<2048, 256, LDS_BYTES, stream>>>(adj, node, b1, c1, b2, c2, bi, bj, wb, out);
}

// Round 6
// 367.364 us; speedup vs baseline: 2.0578x; 1.1094x over previous
//
#include <hip/hip_runtime.h>

typedef _Float16 f16;
typedef f16  f16x8 __attribute__((ext_vector_type(8)));
typedef f16  f16x4 __attribute__((ext_vector_type(4)));
typedef float f32x4 __attribute__((ext_vector_type(4)));
typedef unsigned int u32;

// ---- d_ws layout (f16 elems): hi/lo split weights, 352,256 B ----
#define W1T_HI 0        // [4][128][32]  W1T[e][u][f]
#define W1T_LO 16384
#define V1T_HI 32768    // [128][32]
#define V1T_LO 36864
#define W2T_HI 40960    // [4][64][160]  W2T[e][u][k], k = [h1(128), node(32)]
#define W2T_LO 81920
#define V2T_HI 122880   // [64][32]
#define V2T_LO 124928
#define WIT_HI 126976   // [128][96]     WiT[ua][k], k = [h2(64), node(32)]
#define WIT_LO 139264
#define WJT_HI 151552
#define WJT_LO 163840
#define WS_SRC 88064

// ---- dynamic LDS (bytes): 81,920 B = 80 KB -> 2 blocks/CU ----
// ANNB_LO cols 0..63 are liveness-overlaid as the 8-bit PT_LO plane.
// PTB region doubles as node staging: hi [64][32] f16 + lo [64][32] f16.
#define ADJB_HI 0        // f16 [4][64][64], XOR swizzle (unit8 ^ (m&7))      32768 B
#define ADJB_LO 32768    // u8  [4][64][64], same swizzle, straight bytes    16384 B
#define ANNB_HI 49152    // f16 [64][128]: h1 (h2 overlays cols 64..127)      16384 B
#define ANNB_LO 65536    // u8  [64][128]; cols 0..63 overlay = PT_LO          8192 B
#define PTB     73728    // f16 [64][64] per-wave transposed P/Q; node overlay 8192 B
#define LDS_BYTES 81920

__device__ __forceinline__ f32x4 mfma16(f16x8 a, f16x8 b, f32x4 c){
  return __builtin_amdgcn_mfma_f32_16x16x32_f16(a, b, c, 0, 0, 0);
}
// rcp-based activations: exact at +-inf (rcp(inf)=0), no clamp needed, ~6 VALU ops.
__device__ __forceinline__ float fast_tanh(float x){
  float e = __expf(2.f * x);
  return 1.f - 2.f * __builtin_amdgcn_rcpf(e + 1.f);
}
__device__ __forceinline__ float fast_sigmoid(float x){
  return __builtin_amdgcn_rcpf(1.f + __expf(-x));
}

// ---- 8-bit lo-plane codec (round 6): byte = top 8 bits of f16(lo) = sign +
// 5 exp + 2 man, round-to-nearest via +0x80. Decode places the byte in the
// HIGH byte of each f16 lane (b<<8) -> exact f16 with 2-bit mantissa:
// dec(enc(lo)) = lo*(1+eps), |eps| <= 2^-3. Decode is a pure byte shuffle ->
// 4x v_perm_b32 per 8 elements (was 22 bitwise ops).
__device__ __forceinline__ unsigned char enc1(float lo){
  f16 h = (f16)lo;
  unsigned short u = __builtin_bit_cast(unsigned short, h);
  return (unsigned char)(((u32)u + 0x80u) >> 8);
}
__device__ __forceinline__ void enc8(unsigned char* p, const float* lo){
  u32 a = 0, b = 0;
  #pragma unroll
  for (int j = 0; j < 4; ++j) a |= (u32)enc1(lo[j]) << (8*j);
  #pragma unroll
  for (int j = 0; j < 4; ++j) b |= (u32)enc1(lo[4+j]) << (8*j);
  uint2 v = {a, b};
  *(uint2*)p = v;
}
__device__ __forceinline__ u32 enc4(const float* lo){
  return (u32)enc1(lo[0]) | ((u32)enc1(lo[1]) << 8)
       | ((u32)enc1(lo[2]) << 16) | ((u32)enc1(lo[3]) << 24);
}
__device__ __forceinline__ f16x8 dec8(const unsigned char* p){
  uint2 d = *(const uint2*)p;
  u32 w[4];
  w[0] = __builtin_amdgcn_perm(0u, d.x, 0x010c000cu);  // [0]=0,[1]=b0,[2]=0,[3]=b1
  w[1] = __builtin_amdgcn_perm(0u, d.x, 0x030c020cu);  // b2, b3
  w[2] = __builtin_amdgcn_perm(0u, d.y, 0x010c000cu);  // b4, b5
  w[3] = __builtin_amdgcn_perm(0u, d.y, 0x030c020cu);  // b6, b7
  f16x8 r; __builtin_memcpy(&r, w, 16);
  return r;
}

__global__ void prep_weights(const float* __restrict__ W1, const float* __restrict__ V1,
                             const float* __restrict__ W2, const float* __restrict__ V2,
                             const float* __restrict__ Wi, const float* __restrict__ Wj,
                             f16* __restrict__ ws){
  int i = blockIdx.x * 256 + threadIdx.x;
  if (i >= WS_SRC) return;
  float v; int hi_off, lo_off, idx;
  int j = i;
  if (j < 16384){ int e = j >> 12, u = (j >> 5) & 127, f = j & 31;
    v = W1[(e*32 + f)*128 + u]; hi_off = W1T_HI; lo_off = W1T_LO; idx = j; }
  else if ((j -= 16384) < 4096){ int u = j >> 5, f = j & 31;
    v = V1[f*128 + u]; hi_off = V1T_HI; lo_off = V1T_LO; idx = j; }
  else if ((j -= 4096) < 40960){ int e = j / 10240, r = j % 10240, u = r / 160, k = r % 160;
    v = W2[e*10240 + k*64 + u]; hi_off = W2T_HI; lo_off = W2T_LO; idx = j; }
  else if ((j -= 40960) < 2048){ int u = j >> 5, f = j & 31;
    v = V2[f*64 + u]; hi_off = V2T_HI; lo_off = V2T_LO; idx = j; }
  else if ((j -= 2048) < 12288){ int ua = j / 96, k = j % 96;
    v = Wi[k*128 + ua]; hi_off = WIT_HI; lo_off = WIT_LO; idx = j; }
  else { j -= 12288; int ua = j / 96, k = j % 96;
    v = Wj[k*128 + ua]; hi_off = WJT_HI; lo_off = WJT_LO; idx = j; }
  f16 h = (f16)v;
  ws[hi_off + idx] = h;
  ws[lo_off + idx] = (f16)(v - (float)h);
}

// one block = one batch; 4 waves; 80 KB LDS -> 2 blocks/CU for phase overlap.
__global__ __launch_bounds__(256, 2) void encoder_main(
    const float* __restrict__ adj, const float* __restrict__ node,
    const float* __restrict__ b1, const float* __restrict__ c1,
    const float* __restrict__ b2, const float* __restrict__ c2,
    const float* __restrict__ bi, const float* __restrict__ bj,
    const f16* __restrict__ wb, float* __restrict__ out)
{
  extern __shared__ unsigned char ldsb[];
  f16* adjh            = (f16*)(ldsb + ADJB_HI);
  unsigned char* adjl  = ldsb + ADJB_LO;
  f16* annh            = (f16*)(ldsb + ANNB_HI);
  unsigned char* annl  = ldsb + ANNB_LO;   // cols 0..63 double as PT_LO
  unsigned char* ptb   = ldsb + PTB;       // f16 [64][64], byte-addressed
  f16* nodeH           = (f16*)(ldsb + PTB);          // staging overlay
  f16* nodeLo          = (f16*)(ldsb + PTB + 4096);   // staging overlay

  const int tid  = threadIdx.x;
  const int w    = tid >> 6;
  const int lane = tid & 63;
  const int q    = lane >> 4;
  const int l15  = lane & 15;
  const int b    = blockIdx.x;
  const f32x4 z4 = {0.f, 0.f, 0.f, 0.f};

  // ---------------- stage: adjacency + node -> split LDS ----------------
  {
    const float* ap = adj + (size_t)b * 20480;
    #pragma unroll
    for (int i = 0; i < 8; ++i){
      int fu = tid + 256*i;                       // fu = (e*64 + m)*8 + uc
      int e = fu >> 9, m = (fu >> 3) & 63, uc = fu & 7;
      const float* p = ap + (m*64 + uc*8)*5 + e + 1;    // skip edge type 0
      float v[8], lo[8]; f16x8 hi;
      #pragma unroll
      for (int jj = 0; jj < 8; ++jj) v[jj] = p[jj*5];
      #pragma unroll
      for (int jj = 0; jj < 8; ++jj){
        f16 h = (f16)v[jj]; hi[jj] = h; lo[jj] = v[jj] - (float)h;
      }
      int off = e*4096 + m*64 + ((uc ^ (m & 7)) * 8);
      *(f16x8*)&adjh[off] = hi;
      enc8(&adjl[off], lo);
    }
    const float* np = node + (size_t)b * 2048 + (tid & 63)*32 + (tid >> 6)*8;
    float4 a = *(const float4*)np, c = *(const float4*)(np + 4);
    float v[8] = {a.x, a.y, a.z, a.w, c.x, c.y, c.z, c.w};
    f16x8 hi, lo;
    #pragma unroll
    for (int jj = 0; jj < 8; ++jj){
      f16 h = (f16)v[jj]; hi[jj] = h; lo[jj] = (f16)(v[jj] - (float)h);
    }
    int n = tid & 63, un = tid >> 6;
    *(f16x8*)&nodeH [n*32 + ((un ^ (n & 3)) * 8)] = hi;
    *(f16x8*)&nodeLo[n*32 + ((un ^ (n & 3)) * 8)] = lo;
  }
  __syncthreads();

  // node A-frags hi+lo (registers; node LDS region dead after this + barrier)
  f16x8 anh[4], anl[4];
  #pragma unroll
  for (int mt = 0; mt < 4; ++mt){
    anh[mt] = *(const f16x8*)&nodeH [(mt*16 + l15)*32 + ((q ^ (l15 & 3)) * 8)];
    anl[mt] = *(const f16x8*)&nodeLo[(mt*16 + l15)*32 + ((q ^ (l15 & 3)) * 8)];
  }
  __syncthreads();                                // protect PT/node overlay

  const int ptrow  = (w*16 + l15) * 128;          // PT_HI row byte offset
  const int ptlrow = (w*16 + l15) * 128;          // PT_LO row byte offset (in annl)

  // ============ layer 1: h1 = tanh(sum_e A_e(node@W1+b1) + node@V1 + c1) ============
  f32x4 acc1[4][2];
  #pragma unroll
  for (int mt = 0; mt < 4; ++mt){ acc1[mt][0] = z4; acc1[mt][1] = z4; }

  #pragma unroll
  for (int e = 0; e < 4; ++e){
    f16x8 ah[2][4], al[2][4];
    #pragma unroll
    for (int ks = 0; ks < 2; ++ks)
      #pragma unroll
      for (int mt = 0; mt < 4; ++mt){
        int off = e*4096 + (mt*16 + l15)*64 + (((ks*4 + q) ^ (l15 & 7)) * 8);
        ah[ks][mt] = *(const f16x8*)&adjh[off];
        al[ks][mt] = dec8(&adjl[off]);
      }
    #pragma unroll
    for (int ut = 0; ut < 2; ++ut){
      const int u = w*32 + ut*16 + l15;
      f16x8 wh = *(const f16x8*)&wb[W1T_HI + (e*128 + u)*32 + q*8];
      f16x8 wl = *(const f16x8*)&wb[W1T_LO + (e*128 + u)*32 + q*8];
      float bias = b1[e*128 + u];
      #pragma unroll
      for (int mt = 0; mt < 4; ++mt){
        f32x4 pf = mfma16(anh[mt], wh, z4);
        pf = mfma16(anl[mt], wh, pf);
        pf = mfma16(anh[mt], wl, pf);
        f16x4 ph; float lo4[4];
        #pragma unroll
        for (int r = 0; r < 4; ++r){
          float v = pf[r] + bias;
          f16 h = (f16)v; ph[r] = h; lo4[r] = v - (float)h;
        }
        int unit = ((mt*2 + (q >> 1)) ^ (l15 & 7));      // n0 = mt*16+q*4
        *(f16x4*)(ptb + ptrow + unit*16 + (q & 1)*8) = ph;       // PT_HI[u_loc][n]
        *(u32*)(annl + ptlrow + unit*8 + (q & 1)*4) = enc4(lo4); // PT_LO overlay
      }
      #pragma unroll
      for (int ks = 0; ks < 2; ++ks){
        int pu = ((ks*4 + q) ^ (l15 & 7));
        f16x8 bph = *(const f16x8*)(ptb + ptrow + pu*16);
        f16x8 bpl = dec8(annl + ptlrow + pu*8);
        #pragma unroll
        for (int mt = 0; mt < 4; ++mt){
          acc1[mt][ut] = mfma16(ah[ks][mt], bph, acc1[mt][ut]);
          acc1[mt][ut] = mfma16(al[ks][mt], bph, acc1[mt][ut]);
          acc1[mt][ut] = mfma16(ah[ks][mt], bpl, acc1[mt][ut]);
        }
      }
    }
  }
  __syncthreads();      // PT_LO reads done before ANN_LO cols0..63 h1 writes

  #pragma unroll
  for (int ut = 0; ut < 2; ++ut){
    const int u = w*32 + ut*16 + l15;
    f16x8 wh = *(const f16x8*)&wb[V1T_HI + u*32 + q*8];
    f16x8 wl = *(const f16x8*)&wb[V1T_LO + u*32 + q*8];
    float cv = c1[u];
    #pragma unroll
    for (int mt = 0; mt < 4; ++mt){
      f32x4 a = acc1[mt][ut];
      a = mfma16(anh[mt], wh, a);
      a = mfma16(anl[mt], wh, a);
      a = mfma16(anh[mt], wl, a);
      #pragma unroll
      for (int r = 0; r < 4; ++r){
        float h = fast_tanh(a[r] + cv);
        f16 hh = (f16)h;
        int row = mt*16 + q*4 + r;
        int unit = ((u >> 3) ^ (row & 7));
        annh[row*128 + unit*8 + (u & 7)] = hh;                   // h1 cols 0..127
        annl[row*128 + unit*8 + (u & 7)] = enc1(h - (float)hh);
      }
    }
  }
  __syncthreads();

  // ============ layer 2: h2 = tanh(sum_e A_e(ann@W2+b2) + node@V2 + c2) ============
  const int u2 = w*16 + l15;
  f32x4 qf[4][4];                                 // [e][mt]
  #pragma unroll
  for (int mt = 0; mt < 4; ++mt){
    f16x8 axh[4], axl[4];
    #pragma unroll
    for (int ks = 0; ks < 4; ++ks){
      int off = (mt*16 + l15)*128 + (((ks*4 + q) ^ (l15 & 7)) * 8);
      axh[ks] = *(const f16x8*)&annh[off];
      axl[ks] = dec8(&annl[off]);
    }
    #pragma unroll
    for (int e = 0; e < 4; ++e){
      const f16* w2h = &wb[W2T_HI + (e*64 + u2)*160];
      const f16* w2l = &wb[W2T_LO + (e*64 + u2)*160];
      f16x8 wnh = *(const f16x8*)&w2h[4*32 + q*8];
      f16x8 wnl = *(const f16x8*)&w2l[4*32 + q*8];
      f32x4 t = mfma16(anh[mt], wnh, z4);          // node part k=128..159
      t = mfma16(anl[mt], wnh, t);
      t = mfma16(anh[mt], wnl, t);
      #pragma unroll
      for (int ks = 0; ks < 4; ++ks){
        f16x8 wh = *(const f16x8*)&w2h[ks*32 + q*8];
        f16x8 wl = *(const f16x8*)&w2l[ks*32 + q*8];
        t = mfma16(axh[ks], wh, t);
        t = mfma16(axl[ks], wh, t);
        t = mfma16(axh[ks], wl, t);
      }
      qf[e][mt] = t;
    }
  }
  __syncthreads();      // ANN_LO cols0..63 reads done before QT_LO writes

  f32x4 acc2[4];
  #pragma unroll
  for (int mt = 0; mt < 4; ++mt) acc2[mt] = z4;
  #pragma unroll
  for (int e = 0; e < 4; ++e){
    float bias = b2[e*64 + u2];
    #pragma unroll
    for (int mt = 0; mt < 4; ++mt){
      f16x4 ph; float lo4[4];
      #pragma unroll
      for (int r = 0; r < 4; ++r){
        float v = qf[e][mt][r] + bias;
        f16 h = (f16)v; ph[r] = h; lo4[r] = v - (float)h;
      }
      int unit = ((mt*2 + (q >> 1)) ^ (l15 & 7));
      *(f16x4*)(ptb + ptrow + unit*16 + (q & 1)*8) = ph;       // QT_HI[u_loc][n]
      *(u32*)(annl + ptlrow + unit*8 + (q & 1)*4) = enc4(lo4); // QT_LO overlay
    }
    #pragma unroll
    for (int ks = 0; ks < 2; ++ks){
      int pu = ((ks*4 + q) ^ (l15 & 7));
      f16x8 bph = *(const f16x8*)(ptb + ptrow + pu*16);
      f16x8 bpl = dec8(annl + ptlrow + pu*8);
      #pragma unroll
      for (int mt = 0; mt < 4; ++mt){
        int off = e*4096 + (mt*16 + l15)*64 + (((ks*4 + q) ^ (l15 & 7)) * 8);
        f16x8 ah = *(const f16x8*)&adjh[off];
        f16x8 al = dec8(&adjl[off]);
        acc2[mt] = mfma16(ah, bph, acc2[mt]);
        acc2[mt] = mfma16(al, bph, acc2[mt]);
        acc2[mt] = mfma16(ah, bpl, acc2[mt]);
      }
    }
  }
  {
    f16x8 wh = *(const f16x8*)&wb[V2T_HI + u2*32 + q*8];
    f16x8 wl = *(const f16x8*)&wb[V2T_LO + u2*32 + q*8];
    #pragma unroll
    for (int mt = 0; mt < 4; ++mt){
      acc2[mt] = mfma16(anh[mt], wh, acc2[mt]);
      acc2[mt] = mfma16(anl[mt], wh, acc2[mt]);
      acc2[mt] = mfma16(anh[mt], wl, acc2[mt]);
    }
  }
  // h2 epilogue writes ANN cols 64..127 (units 8..15) — disjoint from QT_LO
  // (units 0..7) and from other waves' QT rows, so no barrier needed here.
  {
    float cv = c2[u2];
    const int uc = 64 + u2;
    #pragma unroll
    for (int mt = 0; mt < 4; ++mt)
      #pragma unroll
      for (int r = 0; r < 4; ++r){
        float h = fast_tanh(acc2[mt][r] + cv);
        f16 hh = (f16)h;
        int row = mt*16 + q*4 + r;
        int unit = ((uc >> 3) ^ (row & 7));
        annh[row*128 + unit*8 + (uc & 7)] = hh;                  // h2 cols 64..127
        annl[row*128 + unit*8 + (uc & 7)] = enc1(h - (float)hh);
      }
  }
  __syncthreads();

  // ============ aggregation: out = tanh(sum_n sigmoid(.)·tanh(.)) ============
  f16x8 wih[2][3], wil[2][3], wjh[2][3], wjl[2][3];
  float bib[2], bjb[2];
  #pragma unroll
  for (int ut = 0; ut < 2; ++ut){
    const int ua = w*32 + ut*16 + l15;
    #pragma unroll
    for (int ks = 0; ks < 3; ++ks){
      wih[ut][ks] = *(const f16x8*)&wb[WIT_HI + ua*96 + ks*32 + q*8];
      wil[ut][ks] = *(const f16x8*)&wb[WIT_LO + ua*96 + ks*32 + q*8];
      wjh[ut][ks] = *(const f16x8*)&wb[WJT_HI + ua*96 + ks*32 + q*8];
      wjl[ut][ks] = *(const f16x8*)&wb[WJT_LO + ua*96 + ks*32 + q*8];
    }
    bib[ut] = bi[ua]; bjb[ut] = bj[ua];
  }
  float s[2] = {0.f, 0.f};
  #pragma unroll
  for (int mt = 0; mt < 4; ++mt){
    f16x8 gh[2], gl[2];
    #pragma unroll
    for (int ks = 0; ks < 2; ++ks){
      int off = (mt*16 + l15)*128 + (((8 + ks*4 + q) ^ (l15 & 7)) * 8);
      gh[ks] = *(const f16x8*)&annh[off];
      gl[ks] = dec8(&annl[off]);
    }
    #pragma unroll
    for (int ut = 0; ut < 2; ++ut){
      f32x4 ia = mfma16(anh[mt], wih[ut][2], z4);   // node part k=64..95
      ia = mfma16(anl[mt], wih[ut][2], ia);
      ia = mfma16(anh[mt], wil[ut][2], ia);
      f32x4 ja = mfma16(anh[mt], wjh[ut][2], z4);
      ja = mfma16(anl[mt], wjh[ut][2], ja);
      ja = mfma16(anh[mt], wjl[ut][2], ja);
      #pragma unroll
      for (int ks = 0; ks < 2; ++ks){
        ia = mfma16(gh[ks], wih[ut][ks], ia);
        ia = mfma16(gl[ks], wih[ut][ks], ia);
        ia = mfma16(gh[ks], wil[ut][ks], ia);
        ja = mfma16(gh[ks], wjh[ut][ks], ja);
        ja = mfma16(gl[ks], wjh[ut][ks], ja);
        ja = mfma16(gh[ks], wjl[ut][ks], ja);
      }
      #pragma unroll
      for (int r = 0; r < 4; ++r)
        s[ut] += fast_sigmoid(ia[r] + bib[ut]) * fast_tanh(ja[r] + bjb[ut]);
    }
  }
  #pragma unroll
  for (int ut = 0; ut < 2; ++ut){
    float t = s[ut];
    t += __shfl_xor(t, 16);
    t += __shfl_xor(t, 32);
    if (q == 0) out[(size_t)b*128 + (w*32 + ut*16 + l15)] = fast_tanh(t);
  }
}

extern "C" void kernel_launch(void* const* d_in, const int* in_sizes, int n_in,
                              void* d_out, int out_size, void* d_ws, size_t ws_size,
                              hipStream_t stream) {
  (void)in_sizes; (void)n_in; (void)out_size; (void)ws_size;
  const float* adj  = (const float*)d_in[0];
  // d_in[1] = hidden (zeros, rank-2): unused by the reference path
  const float* node = (const float*)d_in[2];
  const float* W1   = (const float*)d_in[3];
  const float* b1   = (const float*)d_in[4];
  const float* V1   = (const float*)d_in[5];
  const float* c1   = (const float*)d_in[6];
  const float* W2   = (const float*)d_in[7];
  const float* b2   = (const float*)d_in[8];
  const float* V2   = (const float*)d_in[9];
  const float* c2   = (const float*)d_in[10];
  const float* Wi   = (const float*)d_in[11];
  const float* bi   = (const float*)d_in[12];
  const float* Wj   = (const float*)d_in[13];
  const float* bj   = (const float*)d_in[14];
  f16* wb    = (f16*)d_ws;
  float* out = (float*)d_out;

  hipFuncSetAttribute((const void*)encoder_main,
                      hipFuncAttributeMaxDynamicSharedMemorySize, LDS_BYTES);

  prep_weights<<<(WS_SRC + 255) / 256, 256, 0, stream>>>(W1, V1, W2, V2, Wi, Wj, wb);
  encoder_main<<<2048, 256, LDS_BYTES, stream>>>(adj, node, b1, c1, b2, c2, bi, bj, wb, out);
}